// Round 2
// baseline (915.320 us; speedup 1.0000x reference)
//
#include <hip/hip_runtime.h>
#include <stdint.h>

#define N_TOK 32768
#define DIN   2048
#define DOUT  2048
#define LAD   8
#define RRK   16
#define KCAT  2176   /* DIN + LAD*RRK */
#define SCALE 2.0f

typedef __attribute__((ext_vector_type(8))) short bf16x8;
typedef __attribute__((ext_vector_type(4))) float f32x4;

__device__ __forceinline__ unsigned short f2bf(float f) {
    union { float f; unsigned u; } c; c.f = f;
    return (unsigned short)((c.u + 0x7FFFu + ((c.u >> 16) & 1u)) >> 16);
}

__device__ __forceinline__ uint4 pack8(float4 a, float4 b) {
    union { unsigned short s[8]; uint4 v; } u;
    u.s[0] = f2bf(a.x); u.s[1] = f2bf(a.y); u.s[2] = f2bf(a.z); u.s[3] = f2bf(a.w);
    u.s[4] = f2bf(b.x); u.s[5] = f2bf(b.y); u.s[6] = f2bf(b.z); u.s[7] = f2bf(b.w);
    return u.v;
}

__device__ __forceinline__ void async16(const void* g, void* l) {
    __builtin_amdgcn_global_load_lds(
        (const __attribute__((address_space(1))) void*)g,
        (__attribute__((address_space(3))) void*)l, 16, 0, 0);
}

// LDS tile layout: row-major [rows][32] shorts, 64 B/row = 4 x 16B granules.
// XOR swizzle: data granule g of row r lives at LDS granule g ^ ((r>>1)&3).
// Measured SQ_LDS_BANK_CONFLICT == 0 with this scheme (round 0).

// ---------------------------------------------------------------------------
// P0: build Wcat = [bf16(W) | B_all gathered as [o][l*16+r]]  (DOUT x KCAT)
//     and Acat = bf16(A_all) viewed flat as [128][DIN]
// ---------------------------------------------------------------------------
__global__ __launch_bounds__(256) void prep_w(const float* __restrict__ W,
                                              const float* __restrict__ A_all,
                                              const float* __restrict__ B_all,
                                              unsigned short* __restrict__ wcat,
                                              unsigned short* __restrict__ acat) {
    const int NW = DOUT * DIN / 8;
    const int NB = DOUT * LAD;
    const int NA = LAD * RRK * DIN / 8;
    int tid = blockIdx.x * 256 + threadIdx.x;
    if (tid < NW) {
        int e = tid * 8;
        int o = e / DIN, k = e % DIN;
        float4 f0 = *(const float4*)(W + e);
        float4 f1 = *(const float4*)(W + e + 4);
        *(uint4*)(wcat + (size_t)o * KCAT + k) = pack8(f0, f1);
    } else if (tid < NW + NB) {
        int t = tid - NW;
        int o = t >> 3, l = t & 7;
        const float* src = B_all + ((size_t)l * DOUT + o) * RRK;
        float4 f0 = *(const float4*)(src + 0);
        float4 f1 = *(const float4*)(src + 4);
        float4 f2 = *(const float4*)(src + 8);
        float4 f3 = *(const float4*)(src + 12);
        unsigned short* dst = wcat + (size_t)o * KCAT + DIN + l * RRK;
        *(uint4*)(dst + 0) = pack8(f0, f1);
        *(uint4*)(dst + 8) = pack8(f2, f3);
    } else if (tid < NW + NB + NA) {
        int e = (tid - NW - NB) * 8;
        float4 f0 = *(const float4*)(A_all + e);
        float4 f1 = *(const float4*)(A_all + e + 4);
        *(uint4*)(acat + e) = pack8(f0, f1);
    }
}

// ---------------------------------------------------------------------------
// P1: convert x (fp32) -> xcat[:, 0:DIN] (bf16), ld = KCAT
// ---------------------------------------------------------------------------
__global__ __launch_bounds__(256) void conv_x(const float* __restrict__ x,
                                              unsigned short* __restrict__ xcat) {
    size_t e = ((size_t)blockIdx.x * 256 + threadIdx.x) * 8;
    int n = (int)(e / DIN), k = (int)(e % DIN);
    float4 f0 = *(const float4*)(x + e);
    float4 f1 = *(const float4*)(x + e + 4);
    *(uint4*)(xcat + (size_t)n * KCAT + k) = pack8(f0, f1);
}

// ---------------------------------------------------------------------------
// P2: u_all = xcat[:, :DIN] @ Acat^T  (N x 128, K=2048, bf16 MFMA),
//     mask by lora_idx, * SCALE, write bf16 -> xcat[:, DIN:KCAT]
// ---------------------------------------------------------------------------
__global__ __launch_bounds__(256) void u_gemm(const unsigned short* __restrict__ xcat,
                                              const unsigned short* __restrict__ acat,
                                              const int* __restrict__ lidx,
                                              unsigned short* __restrict__ xcat_w) {
    __shared__ short As[128 * 32];
    __shared__ short Bs[128 * 32];
    const int tid = threadIdx.x;
    const int lane = tid & 63, wv = tid >> 6;
    const int wm = wv >> 1, wn = wv & 1;
    const int quad = lane >> 4, lm = lane & 15;
    const int row0 = blockIdx.x * 128;
    const int sg = (lane & 3) ^ ((lane >> 3) & 3);
    const int swg = quad ^ ((lm >> 1) & 3);

    f32x4 acc[4][4];
    f32x4 zero = {0.f, 0.f, 0.f, 0.f};
#pragma unroll
    for (int i = 0; i < 4; ++i)
#pragma unroll
        for (int j = 0; j < 4; ++j) acc[i][j] = zero;

    for (int kt = 0; kt < DIN / 32; ++kt) {
        const unsigned short* ga = xcat + (size_t)row0 * KCAT + kt * 32;
        const unsigned short* gb = acat + kt * 32;
        __syncthreads();
#pragma unroll
        for (int it = 0; it < 2; ++it) {
            int cw = it * 4 + wv;
            int r = (cw * 64 + lane) >> 2;
            async16(ga + (size_t)r * KCAT + sg * 8, (void*)(As + cw * 512));
            async16(gb + (size_t)r * DIN + sg * 8, (void*)(Bs + cw * 512));
        }
        __syncthreads();
        bf16x8 a[4], b[4];
#pragma unroll
        for (int mi = 0; mi < 4; ++mi)
            a[mi] = *(const bf16x8*)&As[(wm * 64 + mi * 16 + lm) * 32 + swg * 8];
#pragma unroll
        for (int ni = 0; ni < 4; ++ni)
            b[ni] = *(const bf16x8*)&Bs[(wn * 64 + ni * 16 + lm) * 32 + swg * 8];
#pragma unroll
        for (int mi = 0; mi < 4; ++mi)
#pragma unroll
            for (int ni = 0; ni < 4; ++ni)
                acc[mi][ni] = __builtin_amdgcn_mfma_f32_16x16x32_bf16(a[mi], b[ni], acc[mi][ni], 0, 0, 0);
    }

#pragma unroll
    for (int mi = 0; mi < 4; ++mi) {
#pragma unroll
        for (int e = 0; e < 4; ++e) {
            int t = row0 + wm * 64 + mi * 16 + quad * 4 + e;
            int l = lidx[t];
#pragma unroll
            for (int ni = 0; ni < 4; ++ni) {
                int j = wn * 64 + ni * 16 + lm;
                float v = ((j >> 4) == l) ? acc[mi][ni][e] * SCALE : 0.0f;
                xcat_w[(size_t)t * KCAT + DIN + j] = f2bf(v);
            }
        }
    }
}

// ---------------------------------------------------------------------------
// G: out = xcat @ Wcat^T + b   (N x DOUT, K = KCAT = 2176)
// 256x256 tile, BK=32, 512 thr / 8 waves (2M x 4N), per-wave 128x64.
// 4-deep LDS ring (4 x 32 KB = 128 KB), counted vmcnt(8) — loads for tiles
// t+1..t+3 stay in flight across barriers; ONE barrier per K-tile.
// Ring safety: stage at iter t targets buf[(t+3)&3] == buf[(t-1)&3], whose
// last ds_reads completed before this iteration's barrier.
// ---------------------------------------------------------------------------
#define BKT 32
#define NKT (KCAT / BKT)   /* 68 */

__global__ __launch_bounds__(512, 2) void gemm_main(const unsigned short* __restrict__ xcat,
                                                    const unsigned short* __restrict__ wcat,
                                                    const float* __restrict__ bias,
                                                    float* __restrict__ out) {
    __shared__ short As[4][256 * BKT];   // 4 x 16 KB
    __shared__ short Bs[4][256 * BKT];   // 4 x 16 KB
    const int tid = threadIdx.x;
    const int lane = tid & 63, wv = tid >> 6;          // 8 waves
    const int wm = wv >> 2, wn = wv & 3;               // 2 x 4
    const int quad = lane >> 4, lm = lane & 15;

    // XCD-aware bijective swizzle (gridDim.x = 1024, 1024 % 8 == 0):
    // each XCD gets 128 consecutive swz ids = 16 full row-bands (all 8 cols).
    const int orig = blockIdx.x;
    const int swz = (orig & 7) * ((int)gridDim.x >> 3) + (orig >> 3);
    const int col0 = (swz & 7) * 256;
    const int row0 = (swz >> 3) * 256;

    const int sg  = (lane & 3) ^ ((lane >> 3) & 3);    // staging source granule
    const int swg = quad ^ ((lm >> 1) & 3);            // fragment-read granule

    // staging rows: chunk cw = wv (rows 0..127) and cw = 8+wv (rows 128..255)
    const int r0 = (wv * 64 + lane) >> 2;
    const int r1 = ((8 + wv) * 64 + lane) >> 2;
    const unsigned short* gaBase = xcat + (size_t)row0 * KCAT + sg * 8;
    const unsigned short* gbBase = wcat + (size_t)col0 * KCAT + sg * 8;

    f32x4 acc[8][4];
    f32x4 zero = {0.f, 0.f, 0.f, 0.f};
#pragma unroll
    for (int i = 0; i < 8; ++i)
#pragma unroll
        for (int j = 0; j < 4; ++j) acc[i][j] = zero;

    auto stage = [&](int t) {
        const int buf = t & 3;
        const unsigned short* ga = gaBase + t * BKT;
        const unsigned short* gb = gbBase + t * BKT;
        short* la = &As[buf][wv * 512];
        short* lb = &Bs[buf][wv * 512];
        async16(ga + (size_t)r0 * KCAT, (void*)la);
        async16(ga + (size_t)r1 * KCAT, (void*)(la + 4096));
        async16(gb + (size_t)r0 * KCAT, (void*)lb);
        async16(gb + (size_t)r1 * KCAT, (void*)(lb + 4096));
    };

    auto compute = [&](int t) {
        const int buf = t & 3;
        bf16x8 a[8], b[4];
        const short* pa = &As[buf][(wm * 128 + lm) * BKT + swg * 8];
        const short* pb = &Bs[buf][(wn * 64 + lm) * BKT + swg * 8];
#pragma unroll
        for (int mi = 0; mi < 8; ++mi) a[mi] = *(const bf16x8*)(pa + mi * 16 * BKT);
#pragma unroll
        for (int ni = 0; ni < 4; ++ni) b[ni] = *(const bf16x8*)(pb + ni * 16 * BKT);
#pragma unroll
        for (int mi = 0; mi < 8; ++mi)
#pragma unroll
            for (int ni = 0; ni < 4; ++ni)
                acc[mi][ni] = __builtin_amdgcn_mfma_f32_16x16x32_bf16(a[mi], b[ni], acc[mi][ni], 0, 0, 0);
    };

    // prologue: tiles 0..2 in flight (12 loads/thread)
    stage(0); stage(1); stage(2);

    // steady state: tile t landed when <= 8 loads (tiles t+1,t+2) outstanding
    for (int t = 0; t < NKT - 3; ++t) {
        asm volatile("s_waitcnt vmcnt(8)" ::: "memory");
        __builtin_amdgcn_s_barrier();
        asm volatile("" ::: "memory");
        stage(t + 3);
        compute(t);
    }
    // tail: no more stages; outstanding drops 8 -> 4 -> 0
    asm volatile("s_waitcnt vmcnt(8)" ::: "memory");
    __builtin_amdgcn_s_barrier();
    asm volatile("" ::: "memory");
    compute(NKT - 3);

    asm volatile("s_waitcnt vmcnt(4)" ::: "memory");
    __builtin_amdgcn_s_barrier();
    asm volatile("" ::: "memory");
    compute(NKT - 2);

    asm volatile("s_waitcnt vmcnt(0)" ::: "memory");
    __builtin_amdgcn_s_barrier();
    asm volatile("" ::: "memory");
    compute(NKT - 1);

#pragma unroll
    for (int ni = 0; ni < 4; ++ni) {
        int col = col0 + wn * 64 + ni * 16 + lm;
        float bv = bias[col];
#pragma unroll
        for (int mi = 0; mi < 8; ++mi) {
            int rbase = row0 + wm * 128 + mi * 16 + quad * 4;
#pragma unroll
            for (int e = 0; e < 4; ++e)
                out[(size_t)(rbase + e) * DOUT + col] = acc[mi][ni][e] + bv;
        }
    }
}

extern "C" void kernel_launch(void* const* d_in, const int* in_sizes, int n_in,
                              void* d_out, int out_size, void* d_ws, size_t ws_size,
                              hipStream_t stream) {
    const float* x     = (const float*)d_in[0];
    const float* W     = (const float*)d_in[1];
    const float* bias  = (const float*)d_in[2];
    const float* A_all = (const float*)d_in[3];
    const float* B_all = (const float*)d_in[4];
    const int*   lidx  = (const int*)d_in[5];
    float* out = (float*)d_out;

    char* ws = (char*)d_ws;
    unsigned short* xcat = (unsigned short*)ws;
    unsigned short* wcat = (unsigned short*)(ws + (size_t)N_TOK * KCAT * 2);
    unsigned short* acat = (unsigned short*)(ws + (size_t)N_TOK * KCAT * 2
                                                + (size_t)DOUT * KCAT * 2);

    prep_w<<<2240, 256, 0, stream>>>(W, A_all, B_all, wcat, acat);
    conv_x<<<(N_TOK * (DIN / 8)) / 256, 256, 0, stream>>>(x, xcat);
    u_gemm<<<N_TOK / 128, 256, 0, stream>>>(xcat, acat, lidx, xcat);
    gemm_main<<<dim3((N_TOK / 256) * (DOUT / 256)), 512, 0, stream>>>(xcat, wcat, bias, out);
}

// Round 3
// 788.925 us; speedup vs baseline: 1.1602x; 1.1602x over previous
//
#include <hip/hip_runtime.h>
#include <stdint.h>

#define N_TOK 32768
#define DIN   2048
#define DOUT  2048
#define LAD   8
#define RRK   16
#define KCAT  2176   /* DIN + LAD*RRK */
#define SCALE 2.0f

typedef __attribute__((ext_vector_type(8))) short bf16x8;
typedef __attribute__((ext_vector_type(4))) float f32x4;

__device__ __forceinline__ unsigned short f2bf(float f) {
    union { float f; unsigned u; } c; c.f = f;
    return (unsigned short)((c.u + 0x7FFFu + ((c.u >> 16) & 1u)) >> 16);
}

__device__ __forceinline__ uint4 pack8(float4 a, float4 b) {
    union { unsigned short s[8]; uint4 v; } u;
    u.s[0] = f2bf(a.x); u.s[1] = f2bf(a.y); u.s[2] = f2bf(a.z); u.s[3] = f2bf(a.w);
    u.s[4] = f2bf(b.x); u.s[5] = f2bf(b.y); u.s[6] = f2bf(b.z); u.s[7] = f2bf(b.w);
    return u.v;
}

__device__ __forceinline__ void async16(const void* g, void* l) {
    __builtin_amdgcn_global_load_lds(
        (const __attribute__((address_space(1))) void*)g,
        (__attribute__((address_space(3))) void*)l, 16, 0, 0);
}

// ---------------------------------------------------------------------------
// P0: build Wcat = [bf16(W) | B_all gathered as [o][l*16+r]]  (DOUT x KCAT)
//     and Acat = bf16(A_all) viewed flat as [128][DIN]
// ---------------------------------------------------------------------------
__global__ __launch_bounds__(256) void prep_w(const float* __restrict__ W,
                                              const float* __restrict__ A_all,
                                              const float* __restrict__ B_all,
                                              unsigned short* __restrict__ wcat,
                                              unsigned short* __restrict__ acat) {
    const int NW = DOUT * DIN / 8;
    const int NB = DOUT * LAD;
    const int NA = LAD * RRK * DIN / 8;
    int tid = blockIdx.x * 256 + threadIdx.x;
    if (tid < NW) {
        int e = tid * 8;
        int o = e / DIN, k = e % DIN;
        float4 f0 = *(const float4*)(W + e);
        float4 f1 = *(const float4*)(W + e + 4);
        *(uint4*)(wcat + (size_t)o * KCAT + k) = pack8(f0, f1);
    } else if (tid < NW + NB) {
        int t = tid - NW;
        int o = t >> 3, l = t & 7;
        const float* src = B_all + ((size_t)l * DOUT + o) * RRK;
        float4 f0 = *(const float4*)(src + 0);
        float4 f1 = *(const float4*)(src + 4);
        float4 f2 = *(const float4*)(src + 8);
        float4 f3 = *(const float4*)(src + 12);
        unsigned short* dst = wcat + (size_t)o * KCAT + DIN + l * RRK;
        *(uint4*)(dst + 0) = pack8(f0, f1);
        *(uint4*)(dst + 8) = pack8(f2, f3);
    } else if (tid < NW + NB + NA) {
        int e = (tid - NW - NB) * 8;
        float4 f0 = *(const float4*)(A_all + e);
        float4 f1 = *(const float4*)(A_all + e + 4);
        *(uint4*)(acat + e) = pack8(f0, f1);
    }
}

// ---------------------------------------------------------------------------
// P1: convert x (fp32) -> xcat[:, 0:DIN] (bf16), ld = KCAT
// ---------------------------------------------------------------------------
__global__ __launch_bounds__(256) void conv_x(const float* __restrict__ x,
                                              unsigned short* __restrict__ xcat) {
    size_t e = ((size_t)blockIdx.x * 256 + threadIdx.x) * 8;
    int n = (int)(e / DIN), k = (int)(e % DIN);
    float4 f0 = *(const float4*)(x + e);
    float4 f1 = *(const float4*)(x + e + 4);
    *(uint4*)(xcat + (size_t)n * KCAT + k) = pack8(f0, f1);
}

// ---------------------------------------------------------------------------
// P2: u_all = xcat[:, :DIN] @ Acat^T  (N x 128, K=2048, bf16 MFMA),
//     mask by lora_idx, * SCALE, write bf16 -> xcat[:, DIN:KCAT]
// ---------------------------------------------------------------------------
__global__ __launch_bounds__(256) void u_gemm(const unsigned short* __restrict__ xcat,
                                              const unsigned short* __restrict__ acat,
                                              const int* __restrict__ lidx,
                                              unsigned short* __restrict__ xcat_w) {
    __shared__ short As[128 * 32];
    __shared__ short Bs[128 * 32];
    const int tid = threadIdx.x;
    const int lane = tid & 63, wv = tid >> 6;
    const int wm = wv >> 1, wn = wv & 1;
    const int quad = lane >> 4, lm = lane & 15;
    const int row0 = blockIdx.x * 128;
    const int sg = (lane & 3) ^ ((lane >> 3) & 3);
    const int swg = quad ^ ((lm >> 1) & 3);

    f32x4 acc[4][4];
    f32x4 zero = {0.f, 0.f, 0.f, 0.f};
#pragma unroll
    for (int i = 0; i < 4; ++i)
#pragma unroll
        for (int j = 0; j < 4; ++j) acc[i][j] = zero;

    for (int kt = 0; kt < DIN / 32; ++kt) {
        const unsigned short* ga = xcat + (size_t)row0 * KCAT + kt * 32;
        const unsigned short* gb = acat + kt * 32;
        __syncthreads();
#pragma unroll
        for (int it = 0; it < 2; ++it) {
            int cw = it * 4 + wv;
            int r = (cw * 64 + lane) >> 2;
            async16(ga + (size_t)r * KCAT + sg * 8, (void*)(As + cw * 512));
            async16(gb + (size_t)r * DIN + sg * 8, (void*)(Bs + cw * 512));
        }
        __syncthreads();
        bf16x8 a[4], b[4];
#pragma unroll
        for (int mi = 0; mi < 4; ++mi)
            a[mi] = *(const bf16x8*)&As[(wm * 64 + mi * 16 + lm) * 32 + swg * 8];
#pragma unroll
        for (int ni = 0; ni < 4; ++ni)
            b[ni] = *(const bf16x8*)&Bs[(wn * 64 + ni * 16 + lm) * 32 + swg * 8];
#pragma unroll
        for (int mi = 0; mi < 4; ++mi)
#pragma unroll
            for (int ni = 0; ni < 4; ++ni)
                acc[mi][ni] = __builtin_amdgcn_mfma_f32_16x16x32_bf16(a[mi], b[ni], acc[mi][ni], 0, 0, 0);
    }

#pragma unroll
    for (int mi = 0; mi < 4; ++mi) {
#pragma unroll
        for (int e = 0; e < 4; ++e) {
            int t = row0 + wm * 64 + mi * 16 + quad * 4 + e;
            int l = lidx[t];
#pragma unroll
            for (int ni = 0; ni < 4; ++ni) {
                int j = wn * 64 + ni * 16 + lm;
                float v = ((j >> 4) == l) ? acc[mi][ni][e] * SCALE : 0.0f;
                xcat_w[(size_t)t * KCAT + DIN + j] = f2bf(v);
            }
        }
    }
}

// ---------------------------------------------------------------------------
// G: out = xcat @ Wcat^T + b   (N x DOUT, K = KCAT = 2176)
// 8-phase m201-style schedule: 256x256 tile, BK=64, 512 thr / 8 waves (2Mx4N),
// per-wave 128x64. Two 64KB LDS buffers (kt parity), 8 half-tile regions of
// 16KB; each phase stages exactly one half-tile into the region freed one
// phase earlier (B regions dead after q1, A regions after q2). Counted
// vmcnt(4) only at phases P3/P7 (never 0 in main loop).
// LDS swizzle (G4, proven +89%/0-conflict): byte ^= (row&7)<<4, involution,
// applied on pre-swizzled global source (linear LDS dest) and on ds_read.
// ---------------------------------------------------------------------------
#define BK2  64
#define NKT2 (KCAT / BK2)   /* 34 K-tiles */
#define NIT  (NKT2 / 2)     /* 17 iterations */

#define VMC4() asm volatile("s_waitcnt vmcnt(4)" ::: "memory")
#define VMC0() asm volatile("s_waitcnt vmcnt(0)" ::: "memory")
#define LGK8() asm volatile("s_waitcnt lgkmcnt(8)" ::: "memory")
#define LGK0() asm volatile("s_waitcnt lgkmcnt(0)" ::: "memory")
#define BARR() __builtin_amdgcn_s_barrier()
#define SBR()  __builtin_amdgcn_sched_barrier(0)
#define PRIO1() __builtin_amdgcn_s_setprio(1)
#define PRIO0() __builtin_amdgcn_s_setprio(0)

// A fragment read: part = wm, rows (QM*4+mi)*16+lm, k-bytes ks*64+quad*16
#define RD_A(D, QM)                                                            \
    _Pragma("unroll") for (int mi = 0; mi < 4; ++mi)                           \
    _Pragma("unroll") for (int ks = 0; ks < 2; ++ks) {                         \
        const int rl = ((QM) * 4 + mi) * 16 + lm;                              \
        const int ob = (rl * 128 + ks * 64 + quad * 16) ^ ((lm & 7) << 4);     \
        aF[mi * 2 + ks] = *(const bf16x8*)((const char*)&lds[D][wm][0] + ob);  \
    }

// B fragment read: part = 2+(wn>>1), rows (wn&1)*64+(QN*2+ni)*16+lm
#define RD_B(D, QN, BF)                                                        \
    _Pragma("unroll") for (int ni = 0; ni < 2; ++ni)                           \
    _Pragma("unroll") for (int ks = 0; ks < 2; ++ks) {                         \
        const int rl = (wn & 1) * 64 + ((QN) * 2 + ni) * 16 + lm;              \
        const int ob = (rl * 128 + ks * 64 + quad * 16) ^ ((lm & 7) << 4);     \
        BF[ni * 2 + ks] =                                                      \
            *(const bf16x8*)((const char*)&lds[D][2 + (wn >> 1)][0] + ob);     \
    }

// 16 MFMA: one C-quadrant (4 mi x 2 ni) x K=64 (2 ks)
#define MFMA16(QM, QN, BF)                                                     \
    _Pragma("unroll") for (int mi = 0; mi < 4; ++mi)                           \
    _Pragma("unroll") for (int ni = 0; ni < 2; ++ni)                           \
    _Pragma("unroll") for (int ks = 0; ks < 2; ++ks)                           \
        acc[(QM) * 4 + mi][(QN) * 2 + ni] =                                    \
            __builtin_amdgcn_mfma_f32_16x16x32_bf16(                           \
                aF[mi * 2 + ks], BF[ni * 2 + ks],                              \
                acc[(QM) * 4 + mi][(QN) * 2 + ni], 0, 0, 0);

__global__ __launch_bounds__(512, 2) void gemm_main(const unsigned short* __restrict__ xcat,
                                                    const unsigned short* __restrict__ wcat,
                                                    const float* __restrict__ bias,
                                                    float* __restrict__ out) {
    // [buf][part: A-h0, A-h1, B-h0, B-h1][8192 shorts = 128 rows x 64 k]
    __shared__ short lds[2][4][8192];   // 128 KiB
    const int tid = threadIdx.x;
    const int lane = tid & 63, wv = tid >> 6;          // 8 waves
    const int wm = wv >> 2, wn = wv & 3;               // 2 x 4
    const int quad = lane >> 4, lm = lane & 15;

    // XCD-aware bijective swizzle (gridDim.x = 1024, 1024 % 8 == 0)
    const int orig = blockIdx.x;
    const int swz = (orig & 7) * ((int)gridDim.x >> 3) + (orig >> 3);
    const int col0 = (swz & 7) * 256;
    const int row0 = (swz >> 3) * 256;

    // staging per-thread constants: thread writes LDS linear 16B at
    // L = j*8192 + wv*1024 + lane*16; fetches semantic data s(L) where
    // s flips byte bits 4-6 by (row&7). row(L) = j*64 + rbase.
    const int rbase = wv * 8 + (lane >> 3);                               // 0..63
    const int csrc = ((((lane & 7) * 16) ^ (((lane >> 3) & 7) << 4)) >> 1); // shorts

    auto stage = [&](int buf, int part, int gk) {
        const int half = part & 1;
        const unsigned short* g = (part < 2)
            ? xcat + (size_t)(row0 + half * 128) * KCAT
            : wcat + (size_t)(col0 + half * 128) * KCAT;
        short* dbase = &lds[buf][part][0] + wv * 512;   // + lane*16B implicit
#pragma unroll
        for (int j = 0; j < 2; ++j)
            async16(g + (size_t)(j * 64 + rbase) * KCAT + gk * 64 + csrc,
                    (void*)(dbase + j * 4096));
    };

    f32x4 acc[8][4];
    f32x4 zero = {0.f, 0.f, 0.f, 0.f};
#pragma unroll
    for (int i = 0; i < 8; ++i)
#pragma unroll
        for (int j = 0; j < 4; ++j) acc[i][j] = zero;

    bf16x8 aF[8];          // A frags for one qm: [mi(4)][ks(2)]
    bf16x8 bF0[4], bF1[4]; // B frags for qn=0 / qn=1: [ni(2)][ks(2)]

    // prologue: buf0 <- kt0 (A+B), buf1 <- kt1 (B only; kt1 A staged at P0/P1)
    stage(0, 0, 0); stage(0, 1, 0); stage(0, 2, 0); stage(0, 3, 0);
    stage(1, 2, 1); stage(1, 3, 1);
    VMC4();   // drain buf0 kt0 (leaves buf1 B in flight)
    BARR();

    for (int it = 0; it < NIT - 1; ++it) {
        // ---- K-tile 2it (buf 0) ----
        // P0
        RD_A(0, 0) RD_B(0, 0, bF0)
        stage(1, 0, 2 * it + 1); LGK8();
        BARR(); LGK0(); SBR(); PRIO1(); MFMA16(0, 0, bF0) PRIO0(); BARR();
        // P1
        RD_B(0, 1, bF1)
        stage(1, 1, 2 * it + 1);
        BARR(); LGK0(); SBR(); PRIO1(); MFMA16(0, 1, bF1) PRIO0(); BARR();
        // P2
        RD_A(0, 1)
        stage(0, 2, 2 * it + 2);
        BARR(); LGK0(); SBR(); PRIO1(); MFMA16(1, 1, bF1) PRIO0(); BARR();
        // P3
        stage(0, 3, 2 * it + 2);
        BARR(); PRIO1(); MFMA16(1, 0, bF0) PRIO0(); VMC4(); BARR();

        // ---- K-tile 2it+1 (buf 1) ----
        // P4
        RD_A(1, 0) RD_B(1, 0, bF0)
        stage(0, 0, 2 * it + 2); LGK8();
        BARR(); LGK0(); SBR(); PRIO1(); MFMA16(0, 0, bF0) PRIO0(); BARR();
        // P5
        RD_B(1, 1, bF1)
        stage(0, 1, 2 * it + 2);
        BARR(); LGK0(); SBR(); PRIO1(); MFMA16(0, 1, bF1) PRIO0(); BARR();
        // P6
        RD_A(1, 1)
        stage(1, 2, 2 * it + 3);
        BARR(); LGK0(); SBR(); PRIO1(); MFMA16(1, 1, bF1) PRIO0(); BARR();
        // P7
        stage(1, 3, 2 * it + 3);
        BARR(); PRIO1(); MFMA16(1, 0, bF0) PRIO0(); VMC4(); BARR();
    }

    // ---- peeled last iteration (it = NIT-1 = 16; kt 32/33) ----
    // P0
    RD_A(0, 0) RD_B(0, 0, bF0)
    stage(1, 0, 2 * (NIT - 1) + 1); LGK8();
    BARR(); LGK0(); SBR(); PRIO1(); MFMA16(0, 0, bF0) PRIO0(); BARR();
    // P1
    RD_B(0, 1, bF1)
    stage(1, 1, 2 * (NIT - 1) + 1);
    BARR(); LGK0(); SBR(); PRIO1(); MFMA16(0, 1, bF1) PRIO0(); BARR();
    // P2
    RD_A(0, 1)
    BARR(); LGK0(); SBR(); PRIO1(); MFMA16(1, 1, bF1) PRIO0(); BARR();
    // P3 — drain everything (kt33 A was staged at P0/P1 above)
    BARR(); PRIO1(); MFMA16(1, 0, bF0) PRIO0(); VMC0(); BARR();
    // P4
    RD_A(1, 0) RD_B(1, 0, bF0)
    BARR(); LGK0(); SBR(); PRIO1(); MFMA16(0, 0, bF0) PRIO0(); BARR();
    // P5
    RD_B(1, 1, bF1)
    BARR(); LGK0(); SBR(); PRIO1(); MFMA16(0, 1, bF1) PRIO0(); BARR();
    // P6
    RD_A(1, 1)
    BARR(); LGK0(); SBR(); PRIO1(); MFMA16(1, 1, bF1) PRIO0(); BARR();
    // P7
    PRIO1(); MFMA16(1, 0, bF0) PRIO0();

    // epilogue
#pragma unroll
    for (int ni = 0; ni < 4; ++ni) {
        int col = col0 + wn * 64 + ni * 16 + lm;
        float bv = bias[col];
#pragma unroll
        for (int mi = 0; mi < 8; ++mi) {
            int rbase2 = row0 + wm * 128 + mi * 16 + quad * 4;
#pragma unroll
            for (int e = 0; e < 4; ++e)
                out[(size_t)(rbase2 + e) * DOUT + col] = acc[mi][ni][e] + bv;
        }
    }
}

extern "C" void kernel_launch(void* const* d_in, const int* in_sizes, int n_in,
                              void* d_out, int out_size, void* d_ws, size_t ws_size,
                              hipStream_t stream) {
    const float* x     = (const float*)d_in[0];
    const float* W     = (const float*)d_in[1];
    const float* bias  = (const float*)d_in[2];
    const float* A_all = (const float*)d_in[3];
    const float* B_all = (const float*)d_in[4];
    const int*   lidx  = (const int*)d_in[5];
    float* out = (float*)d_out;

    char* ws = (char*)d_ws;
    unsigned short* xcat = (unsigned short*)ws;
    unsigned short* wcat = (unsigned short*)(ws + (size_t)N_TOK * KCAT * 2);
    unsigned short* acat = (unsigned short*)(ws + (size_t)N_TOK * KCAT * 2
                                                + (size_t)DOUT * KCAT * 2);

    prep_w<<<2240, 256, 0, stream>>>(W, A_all, B_all, wcat, acat);
    conv_x<<<(N_TOK * (DIN / 8)) / 256, 256, 0, stream>>>(x, xcat);
    u_gemm<<<N_TOK / 128, 256, 0, stream>>>(xcat, acat, lidx, xcat);
    gemm_main<<<dim3((N_TOK / 256) * (DOUT / 256)), 512, 0, stream>>>(xcat, wcat, bias, out);
}

// Round 4
// 772.673 us; speedup vs baseline: 1.1846x; 1.0210x over previous
//
#include <hip/hip_runtime.h>
#include <stdint.h>

#define N_TOK 32768
#define DIN   2048
#define DOUT  2048
#define LAD   8
#define RRK   16
#define KCAT  2176   /* DIN + LAD*RRK */
#define SCALE 2.0f

typedef __attribute__((ext_vector_type(8))) short bf16x8;
typedef __attribute__((ext_vector_type(4))) float f32x4;

__device__ __forceinline__ unsigned short f2bf(float f) {
    union { float f; unsigned u; } c; c.f = f;
    return (unsigned short)((c.u + 0x7FFFu + ((c.u >> 16) & 1u)) >> 16);
}

__device__ __forceinline__ uint4 pack8(float4 a, float4 b) {
    union { unsigned short s[8]; uint4 v; } u;
    u.s[0] = f2bf(a.x); u.s[1] = f2bf(a.y); u.s[2] = f2bf(a.z); u.s[3] = f2bf(a.w);
    u.s[4] = f2bf(b.x); u.s[5] = f2bf(b.y); u.s[6] = f2bf(b.z); u.s[7] = f2bf(b.w);
    return u.v;
}

__device__ __forceinline__ bf16x8 cvt8(float4 a, float4 b) {
    union { uint4 v; bf16x8 h; } u;
    u.v = pack8(a, b);
    return u.h;
}

__device__ __forceinline__ void async16(const void* g, void* l) {
    __builtin_amdgcn_global_load_lds(
        (const __attribute__((address_space(1))) void*)g,
        (__attribute__((address_space(3))) void*)l, 16, 0, 0);
}

// ---------------------------------------------------------------------------
// P0: build Wcat = [bf16(W) | B_all gathered as [o][l*16+r]]  (DOUT x KCAT)
//     and Acat = bf16(A_all) viewed flat as [128][DIN]
// ---------------------------------------------------------------------------
__global__ __launch_bounds__(256) void prep_w(const float* __restrict__ W,
                                              const float* __restrict__ A_all,
                                              const float* __restrict__ B_all,
                                              unsigned short* __restrict__ wcat,
                                              unsigned short* __restrict__ acat) {
    const int NW = DOUT * DIN / 8;
    const int NB = DOUT * LAD;
    const int NA = LAD * RRK * DIN / 8;
    int tid = blockIdx.x * 256 + threadIdx.x;
    if (tid < NW) {
        int e = tid * 8;
        int o = e / DIN, k = e % DIN;
        float4 f0 = *(const float4*)(W + e);
        float4 f1 = *(const float4*)(W + e + 4);
        *(uint4*)(wcat + (size_t)o * KCAT + k) = pack8(f0, f1);
    } else if (tid < NW + NB) {
        int t = tid - NW;
        int o = t >> 3, l = t & 7;
        const float* src = B_all + ((size_t)l * DOUT + o) * RRK;
        float4 f0 = *(const float4*)(src + 0);
        float4 f1 = *(const float4*)(src + 4);
        float4 f2 = *(const float4*)(src + 8);
        float4 f3 = *(const float4*)(src + 12);
        unsigned short* dst = wcat + (size_t)o * KCAT + DIN + l * RRK;
        *(uint4*)(dst + 0) = pack8(f0, f1);
        *(uint4*)(dst + 8) = pack8(f2, f3);
    } else if (tid < NW + NB + NA) {
        int e = (tid - NW - NB) * 8;
        float4 f0 = *(const float4*)(A_all + e);
        float4 f1 = *(const float4*)(A_all + e + 4);
        *(uint4*)(acat + e) = pack8(f0, f1);
    }
}

// ---------------------------------------------------------------------------
// XU (fused conv_x + u_gemm): read x fp32 ONCE; write bf16 xcat[:, :DIN];
// compute u = x @ Acat^T (K=2048), mask by lora_idx, *SCALE -> xcat[:, DIN:].
// 256 blocks x 512 thr (8 waves). A-fragments come STRAIGHT from registers:
// lane (quad,lm) of wave w loads x[row0+w*16+lm][kt*64 + ks*32 + quad*8 ..+8]
// -- exactly the 16x16x32 A-frag layout, coalesced 128 B per (lm,ks) group.
// acat staged via 2-deep LDS ring + counted vmcnt(2) (never 0 mid-loop).
// ---------------------------------------------------------------------------
__global__ __launch_bounds__(512, 2) void xu_gemm(const float* __restrict__ x,
                                                  const unsigned short* __restrict__ acat,
                                                  const int* __restrict__ lidx,
                                                  unsigned short* __restrict__ xcat) {
    __shared__ short Bs[2][8192];   // [buf][128 feat rows x 64 k], G4-swizzled
    const int tid = threadIdx.x;
    const int lane = tid & 63, wv = tid >> 6;
    const int quad = lane >> 4, lm = lane & 15;
    const int row0 = blockIdx.x * 128;

    // staging math (same proven scheme as gemm_main): linear LDS dest,
    // pre-swizzled global source; swizzle byte ^= (row&7)<<4
    const int rbase = wv * 8 + (lane >> 3);
    const int csrc = ((((lane & 7) * 16) ^ (((lane >> 3) & 7) << 4)) >> 1);

    auto stageB = [&](int kt, int buf) {
        short* dbase = &Bs[buf][0] + wv * 512;
#pragma unroll
        for (int j = 0; j < 2; ++j)
            async16(acat + (size_t)(j * 64 + rbase) * DIN + kt * 64 + csrc,
                    (void*)(dbase + j * 4096));
    };

    const int myrow = row0 + wv * 16 + lm;
    const float* gx = x + (size_t)myrow * DIN + quad * 8;
    unsigned short* gxc = xcat + (size_t)myrow * KCAT + quad * 8;

    f32x4 acc[8];
    f32x4 zero = {0.f, 0.f, 0.f, 0.f};
#pragma unroll
    for (int i = 0; i < 8; ++i) acc[i] = zero;

    stageB(0, 0);
    stageB(1, 1);
    asm volatile("s_waitcnt vmcnt(2)" ::: "memory");
    __builtin_amdgcn_s_barrier();

    for (int t = 0; t < 32; ++t) {
        const int buf = t & 1;
        // B fragments from LDS (compiler tracks lgkm deps)
        bf16x8 bF[16];
#pragma unroll
        for (int nj = 0; nj < 8; ++nj)
#pragma unroll
            for (int ks = 0; ks < 2; ++ks) {
                const int rl = nj * 16 + lm;
                const int ob = (rl * 128 + ks * 64 + quad * 16) ^ ((lm & 7) << 4);
                bF[nj * 2 + ks] = *(const bf16x8*)((const char*)&Bs[buf][0] + ob);
            }
        // x loads (4 vmem)
        float4 xa0 = *(const float4*)(gx + t * 64 + 0);
        float4 xa1 = *(const float4*)(gx + t * 64 + 4);
        float4 xb0 = *(const float4*)(gx + t * 64 + 32);
        float4 xb1 = *(const float4*)(gx + t * 64 + 36);
        asm volatile("s_waitcnt lgkmcnt(0)" ::: "memory");
        __builtin_amdgcn_s_barrier();          // all waves done reading Bs[buf]
        stageB(t + 2 < 32 ? t + 2 : 31, buf);  // uniform: dummy re-stage at tail
        if (t < 31)
            asm volatile("s_waitcnt vmcnt(2)" ::: "memory");  // x + stage(t+1) landed
        else
            asm volatile("s_waitcnt vmcnt(0)" ::: "memory");
        // convert + write bf16 x to xcat
        bf16x8 aF0 = cvt8(xa0, xa1);
        bf16x8 aF1 = cvt8(xb0, xb1);
        union { bf16x8 h; uint4 v; } s0, s1;
        s0.h = aF0; s1.h = aF1;
        *(uint4*)(gxc + t * 64 + 0)  = s0.v;
        *(uint4*)(gxc + t * 64 + 32) = s1.v;
#pragma unroll
        for (int nj = 0; nj < 8; ++nj) {
            acc[nj] = __builtin_amdgcn_mfma_f32_16x16x32_bf16(aF0, bF[nj * 2 + 0], acc[nj], 0, 0, 0);
            acc[nj] = __builtin_amdgcn_mfma_f32_16x16x32_bf16(aF1, bF[nj * 2 + 1], acc[nj], 0, 0, 0);
        }
        __builtin_amdgcn_s_barrier();          // stage(t+1) landed for ALL waves
    }

    // masked, scaled u -> xcat[:, DIN:]
#pragma unroll
    for (int e = 0; e < 4; ++e) {
        int t = row0 + wv * 16 + quad * 4 + e;
        int l = lidx[t];
#pragma unroll
        for (int nj = 0; nj < 8; ++nj) {
            float v = (nj == l) ? acc[nj][e] * SCALE : 0.0f;
            xcat[(size_t)t * KCAT + DIN + nj * 16 + lm] = f2bf(v);
        }
    }
}

// ---------------------------------------------------------------------------
// G: out = xcat @ Wcat^T + b   (N x DOUT, K = KCAT = 2176)
// 8-phase schedule, 256x256 tile, BK=64, 512 thr / 8 waves (2Mx4N).
// Read distribution rebalanced 12/4/8/0 -> 8/4/8/4: bF0 for K-tile kt is read
// in the PRECEDING tile's P3/P7 slot, immediately after that phase's vmcnt(4)
// (at which point B-h0 of kt is provably landed: the vmcnt leaves only the 4
// newest stage-loads outstanding, and B-h0 is always older than those).
// ---------------------------------------------------------------------------
#define BK2  64
#define NKT2 (KCAT / BK2)   /* 34 K-tiles */
#define NIT  (NKT2 / 2)     /* 17 iterations */

#define VMC4() asm volatile("s_waitcnt vmcnt(4)" ::: "memory")
#define VMC0() asm volatile("s_waitcnt vmcnt(0)" ::: "memory")
#define LGK8() asm volatile("s_waitcnt lgkmcnt(8)" ::: "memory")
#define LGK0() asm volatile("s_waitcnt lgkmcnt(0)" ::: "memory")
#define BARR() __builtin_amdgcn_s_barrier()
#define SBR()  __builtin_amdgcn_sched_barrier(0)
#define PRIO1() __builtin_amdgcn_s_setprio(1)
#define PRIO0() __builtin_amdgcn_s_setprio(0)

#define RD_A(D, QM)                                                            \
    _Pragma("unroll") for (int mi = 0; mi < 4; ++mi)                           \
    _Pragma("unroll") for (int ks = 0; ks < 2; ++ks) {                         \
        const int rl = ((QM) * 4 + mi) * 16 + lm;                              \
        const int ob = (rl * 128 + ks * 64 + quad * 16) ^ ((lm & 7) << 4);     \
        aF[mi * 2 + ks] = *(const bf16x8*)((const char*)&lds[D][wm][0] + ob);  \
    }

#define RD_B(D, QN, BF)                                                        \
    _Pragma("unroll") for (int ni = 0; ni < 2; ++ni)                           \
    _Pragma("unroll") for (int ks = 0; ks < 2; ++ks) {                         \
        const int rl = (wn & 1) * 64 + ((QN) * 2 + ni) * 16 + lm;              \
        const int ob = (rl * 128 + ks * 64 + quad * 16) ^ ((lm & 7) << 4);     \
        BF[ni * 2 + ks] =                                                      \
            *(const bf16x8*)((const char*)&lds[D][2 + (wn >> 1)][0] + ob);     \
    }

#define MFMA16(QM, QN, BF)                                                     \
    _Pragma("unroll") for (int mi = 0; mi < 4; ++mi)                           \
    _Pragma("unroll") for (int ni = 0; ni < 2; ++ni)                           \
    _Pragma("unroll") for (int ks = 0; ks < 2; ++ks)                           \
        acc[(QM) * 4 + mi][(QN) * 2 + ni] =                                    \
            __builtin_amdgcn_mfma_f32_16x16x32_bf16(                           \
                aF[mi * 2 + ks], BF[ni * 2 + ks],                              \
                acc[(QM) * 4 + mi][(QN) * 2 + ni], 0, 0, 0);

__global__ __launch_bounds__(512, 2) void gemm_main(const unsigned short* __restrict__ xcat,
                                                    const unsigned short* __restrict__ wcat,
                                                    const float* __restrict__ bias,
                                                    float* __restrict__ out) {
    __shared__ short lds[2][4][8192];   // 128 KiB
    const int tid = threadIdx.x;
    const int lane = tid & 63, wv = tid >> 6;
    const int wm = wv >> 2, wn = wv & 3;
    const int quad = lane >> 4, lm = lane & 15;

    const int orig = blockIdx.x;
    const int swz = (orig & 7) * ((int)gridDim.x >> 3) + (orig >> 3);
    const int col0 = (swz & 7) * 256;
    const int row0 = (swz >> 3) * 256;

    const int rbase = wv * 8 + (lane >> 3);
    const int csrc = ((((lane & 7) * 16) ^ (((lane >> 3) & 7) << 4)) >> 1);

    auto stage = [&](int buf, int part, int gk) {
        const int half = part & 1;
        const unsigned short* g = (part < 2)
            ? xcat + (size_t)(row0 + half * 128) * KCAT
            : wcat + (size_t)(col0 + half * 128) * KCAT;
        short* dbase = &lds[buf][part][0] + wv * 512;
#pragma unroll
        for (int j = 0; j < 2; ++j)
            async16(g + (size_t)(j * 64 + rbase) * KCAT + gk * 64 + csrc,
                    (void*)(dbase + j * 4096));
    };

    f32x4 acc[8][4];
    f32x4 zero = {0.f, 0.f, 0.f, 0.f};
#pragma unroll
    for (int i = 0; i < 8; ++i)
#pragma unroll
        for (int j = 0; j < 4; ++j) acc[i][j] = zero;

    bf16x8 aF[8];
    bf16x8 bF0[4], bF1[4];

    // prologue: buf0 <- kt0 (A+B), buf1 <- kt1 (B only)
    stage(0, 0, 0); stage(0, 1, 0); stage(0, 2, 0); stage(0, 3, 0);
    stage(1, 2, 1); stage(1, 3, 1);
    VMC4();
    BARR();
    RD_B(0, 0, bF0)   // kt0's B-h0 (landed; lgkm covered by P0's LGK0)

    for (int it = 0; it < NIT - 1; ++it) {
        // ---- K-tile 2it (buf 0) ----
        // P0
        RD_A(0, 0)
        stage(1, 0, 2 * it + 1); LGK8();
        BARR(); LGK0(); SBR(); PRIO1(); MFMA16(0, 0, bF0) PRIO0(); BARR();
        // P1
        RD_B(0, 1, bF1)
        stage(1, 1, 2 * it + 1);
        BARR(); LGK0(); SBR(); PRIO1(); MFMA16(0, 1, bF1) PRIO0(); BARR();
        // P2
        RD_A(0, 1)
        stage(0, 2, 2 * it + 2);
        BARR(); LGK0(); SBR(); PRIO1(); MFMA16(1, 1, bF1) PRIO0(); BARR();
        // P3  (+ read NEXT tile's bF0 from buf1, landed at VMC4)
        stage(0, 3, 2 * it + 2);
        BARR(); PRIO1(); MFMA16(1, 0, bF0) PRIO0(); VMC4();
        RD_B(1, 0, bF0)
        BARR();

        // ---- K-tile 2it+1 (buf 1) ----
        // P4
        RD_A(1, 0)
        stage(0, 0, 2 * it + 2); LGK8();
        BARR(); LGK0(); SBR(); PRIO1(); MFMA16(0, 0, bF0) PRIO0(); BARR();
        // P5
        RD_B(1, 1, bF1)
        stage(0, 1, 2 * it + 2);
        BARR(); LGK0(); SBR(); PRIO1(); MFMA16(0, 1, bF1) PRIO0(); BARR();
        // P6
        RD_A(1, 1)
        stage(1, 2, 2 * it + 3);
        BARR(); LGK0(); SBR(); PRIO1(); MFMA16(1, 1, bF1) PRIO0(); BARR();
        // P7  (+ read next buf0-tile's bF0, landed at VMC4)
        stage(1, 3, 2 * it + 3);
        BARR(); PRIO1(); MFMA16(1, 0, bF0) PRIO0(); VMC4();
        RD_B(0, 0, bF0)
        BARR();
    }

    // ---- peeled last iteration (kt 32/33) ----
    // P0
    RD_A(0, 0)
    stage(1, 0, 2 * (NIT - 1) + 1); LGK8();
    BARR(); LGK0(); SBR(); PRIO1(); MFMA16(0, 0, bF0) PRIO0(); BARR();
    // P1
    RD_B(0, 1, bF1)
    stage(1, 1, 2 * (NIT - 1) + 1);
    BARR(); LGK0(); SBR(); PRIO1(); MFMA16(0, 1, bF1) PRIO0(); BARR();
    // P2
    RD_A(0, 1)
    BARR(); LGK0(); SBR(); PRIO1(); MFMA16(1, 1, bF1) PRIO0(); BARR();
    // P3 — drain everything, then read kt33's bF0
    BARR(); PRIO1(); MFMA16(1, 0, bF0) PRIO0(); VMC0();
    RD_B(1, 0, bF0)
    BARR();
    // P4
    RD_A(1, 0)
    BARR(); LGK0(); SBR(); PRIO1(); MFMA16(0, 0, bF0) PRIO0(); BARR();
    // P5
    RD_B(1, 1, bF1)
    BARR(); LGK0(); SBR(); PRIO1(); MFMA16(0, 1, bF1) PRIO0(); BARR();
    // P6
    RD_A(1, 1)
    BARR(); LGK0(); SBR(); PRIO1(); MFMA16(1, 1, bF1) PRIO0(); BARR();
    // P7
    PRIO1(); MFMA16(1, 0, bF0) PRIO0();

    // epilogue
#pragma unroll
    for (int ni = 0; ni < 4; ++ni) {
        int col = col0 + wn * 64 + ni * 16 + lm;
        float bv = bias[col];
#pragma unroll
        for (int mi = 0; mi < 8; ++mi) {
            int rbase2 = row0 + wm * 128 + mi * 16 + quad * 4;
#pragma unroll
            for (int e = 0; e < 4; ++e)
                out[(size_t)(rbase2 + e) * DOUT + col] = acc[mi][ni][e] + bv;
        }
    }
}

extern "C" void kernel_launch(void* const* d_in, const int* in_sizes, int n_in,
                              void* d_out, int out_size, void* d_ws, size_t ws_size,
                              hipStream_t stream) {
    const float* x     = (const float*)d_in[0];
    const float* W     = (const float*)d_in[1];
    const float* bias  = (const float*)d_in[2];
    const float* A_all = (const float*)d_in[3];
    const float* B_all = (const float*)d_in[4];
    const int*   lidx  = (const int*)d_in[5];
    float* out = (float*)d_out;

    char* ws = (char*)d_ws;
    unsigned short* xcat = (unsigned short*)ws;
    unsigned short* wcat = (unsigned short*)(ws + (size_t)N_TOK * KCAT * 2);
    unsigned short* acat = (unsigned short*)(ws + (size_t)N_TOK * KCAT * 2
                                                + (size_t)DOUT * KCAT * 2);

    prep_w<<<2240, 256, 0, stream>>>(W, A_all, B_all, wcat, acat);
    xu_gemm<<<N_TOK / 128, 512, 0, stream>>>(x, acat, lidx, xcat);
    gemm_main<<<dim3((N_TOK / 256) * (DOUT / 256)), 512, 0, stream>>>(xcat, wcat, bias, out);
}

// Round 5
// 771.255 us; speedup vs baseline: 1.1868x; 1.0018x over previous
//
#include <hip/hip_runtime.h>
#include <stdint.h>

#define N_TOK 32768
#define DIN   2048
#define DOUT  2048
#define LAD   8
#define RRK   16
#define KCAT  2176   /* DIN + LAD*RRK */
#define SCALE 2.0f

typedef __attribute__((ext_vector_type(8))) short bf16x8;
typedef __attribute__((ext_vector_type(4))) float f32x4;

__device__ __forceinline__ unsigned short f2bf(float f) {
    union { float f; unsigned u; } c; c.f = f;
    return (unsigned short)((c.u + 0x7FFFu + ((c.u >> 16) & 1u)) >> 16);
}

__device__ __forceinline__ uint4 pack8(float4 a, float4 b) {
    union { unsigned short s[8]; uint4 v; } u;
    u.s[0] = f2bf(a.x); u.s[1] = f2bf(a.y); u.s[2] = f2bf(a.z); u.s[3] = f2bf(a.w);
    u.s[4] = f2bf(b.x); u.s[5] = f2bf(b.y); u.s[6] = f2bf(b.z); u.s[7] = f2bf(b.w);
    return u.v;
}

__device__ __forceinline__ bf16x8 cvt8(float4 a, float4 b) {
    union { uint4 v; bf16x8 h; } u;
    u.v = pack8(a, b);
    return u.h;
}

__device__ __forceinline__ void async16(const void* g, void* l) {
    __builtin_amdgcn_global_load_lds(
        (const __attribute__((address_space(1))) void*)g,
        (__attribute__((address_space(3))) void*)l, 16, 0, 0);
}

// ---------------------------------------------------------------------------
// P0: build Wcat = [bf16(W) | B_all gathered as [o][l*16+r]]  (DOUT x KCAT)
//     and Acat = bf16(A_all) viewed flat as [128][DIN]
// ---------------------------------------------------------------------------
__global__ __launch_bounds__(256) void prep_w(const float* __restrict__ W,
                                              const float* __restrict__ A_all,
                                              const float* __restrict__ B_all,
                                              unsigned short* __restrict__ wcat,
                                              unsigned short* __restrict__ acat) {
    const int NW = DOUT * DIN / 8;
    const int NB = DOUT * LAD;
    const int NA = LAD * RRK * DIN / 8;
    int tid = blockIdx.x * 256 + threadIdx.x;
    if (tid < NW) {
        int e = tid * 8;
        int o = e / DIN, k = e % DIN;
        float4 f0 = *(const float4*)(W + e);
        float4 f1 = *(const float4*)(W + e + 4);
        *(uint4*)(wcat + (size_t)o * KCAT + k) = pack8(f0, f1);
    } else if (tid < NW + NB) {
        int t = tid - NW;
        int o = t >> 3, l = t & 7;
        const float* src = B_all + ((size_t)l * DOUT + o) * RRK;
        float4 f0 = *(const float4*)(src + 0);
        float4 f1 = *(const float4*)(src + 4);
        float4 f2 = *(const float4*)(src + 8);
        float4 f3 = *(const float4*)(src + 12);
        unsigned short* dst = wcat + (size_t)o * KCAT + DIN + l * RRK;
        *(uint4*)(dst + 0) = pack8(f0, f1);
        *(uint4*)(dst + 8) = pack8(f2, f3);
    } else if (tid < NW + NB + NA) {
        int e = (tid - NW - NB) * 8;
        float4 f0 = *(const float4*)(A_all + e);
        float4 f1 = *(const float4*)(A_all + e + 4);
        *(uint4*)(acat + e) = pack8(f0, f1);
    }
}

// ---------------------------------------------------------------------------
// XU (fused conv_x + u_gemm), v2: chunked-LDS, barrier-light.
// acat (128 x 2048 bf16) staged in 4 chunks of K=512 (8 swizzled [128][64]
// subtiles = 128 KB). Inner loop: 8 K-steps with NO barriers — per-wave
// compiler-scheduled waits only; x-loads/cvt/stores/ds_reads/MFMA free-run.
// Barriers: 2 per chunk (8 total) instead of 96.
// A-fragments straight from registers (x fp32 -> cvt8), x read ONCE.
// ---------------------------------------------------------------------------
__global__ __launch_bounds__(512, 2) void xu_gemm(const float* __restrict__ x,
                                                  const unsigned short* __restrict__ acat,
                                                  const int* __restrict__ lidx,
                                                  unsigned short* __restrict__ xcat) {
    __shared__ short Bs[8][8192];   // 8 subtiles x [128 rows x 64 k], 128 KB
    const int tid = threadIdx.x;
    const int lane = tid & 63, wv = tid >> 6;
    const int quad = lane >> 4, lm = lane & 15;
    const int row0 = blockIdx.x * 128;

    // staging math (proven scheme): linear LDS dest, pre-swizzled global src;
    // swizzle byte ^= (row&7)<<4, row&7 == (lane>>3)&7 for this pattern.
    const int rbase = wv * 8 + (lane >> 3);
    const int csrc = ((((lane & 7) * 16) ^ (((lane >> 3) & 7) << 4)) >> 1);

    const int myrow = row0 + wv * 16 + lm;
    const float* gx = x + (size_t)myrow * DIN + quad * 8;
    unsigned short* gxc = xcat + (size_t)myrow * KCAT + quad * 8;

    f32x4 acc[8];
    f32x4 zero = {0.f, 0.f, 0.f, 0.f};
#pragma unroll
    for (int i = 0; i < 8; ++i) acc[i] = zero;

    for (int c = 0; c < 4; ++c) {
        __syncthreads();   // prior chunk's reads complete before overwrite
#pragma unroll
        for (int st = 0; st < 8; ++st) {
            short* dbase = &Bs[st][0] + wv * 512;
#pragma unroll
            for (int j = 0; j < 2; ++j)
                async16(acat + (size_t)(j * 64 + rbase) * DIN + (c * 8 + st) * 64 + csrc,
                        (void*)(dbase + j * 4096));
        }
        asm volatile("s_waitcnt vmcnt(0)" ::: "memory");
        __syncthreads();

#pragma unroll
        for (int st = 0; st < 8; ++st) {
            const int t = c * 8 + st;
            // x loads (compiler hoists/schedules freely — no fences here)
            float4 xa0 = *(const float4*)(gx + t * 64 + 0);
            float4 xa1 = *(const float4*)(gx + t * 64 + 4);
            float4 xb0 = *(const float4*)(gx + t * 64 + 32);
            float4 xb1 = *(const float4*)(gx + t * 64 + 36);
            bf16x8 aF0 = cvt8(xa0, xa1);
            bf16x8 aF1 = cvt8(xb0, xb1);
            union { bf16x8 h; uint4 v; } s0, s1;
            s0.h = aF0; s1.h = aF1;
            *(uint4*)(gxc + t * 64 + 0)  = s0.v;
            *(uint4*)(gxc + t * 64 + 32) = s1.v;
            // B fragments from LDS
            bf16x8 bF[16];
#pragma unroll
            for (int nj = 0; nj < 8; ++nj)
#pragma unroll
                for (int ks = 0; ks < 2; ++ks) {
                    const int rl = nj * 16 + lm;
                    const int ob = (rl * 128 + ks * 64 + quad * 16) ^ ((lm & 7) << 4);
                    bF[nj * 2 + ks] = *(const bf16x8*)((const char*)&Bs[st][0] + ob);
                }
            // dependent pairs (same acc, ks=0 -> ks=1) spaced 8 apart
#pragma unroll
            for (int nj = 0; nj < 8; ++nj)
                acc[nj] = __builtin_amdgcn_mfma_f32_16x16x32_bf16(aF0, bF[nj * 2 + 0], acc[nj], 0, 0, 0);
#pragma unroll
            for (int nj = 0; nj < 8; ++nj)
                acc[nj] = __builtin_amdgcn_mfma_f32_16x16x32_bf16(aF1, bF[nj * 2 + 1], acc[nj], 0, 0, 0);
        }
    }

    // masked, scaled u -> xcat[:, DIN:]
#pragma unroll
    for (int e = 0; e < 4; ++e) {
        int t = row0 + wv * 16 + quad * 4 + e;
        int l = lidx[t];
#pragma unroll
        for (int nj = 0; nj < 8; ++nj) {
            float v = (nj == l) ? acc[nj][e] * SCALE : 0.0f;
            xcat[(size_t)t * KCAT + DIN + nj * 16 + lm] = f2bf(v);
        }
    }
}

// ---------------------------------------------------------------------------
// G: out = xcat @ Wcat^T + b   (N x DOUT, K = KCAT = 2176)
// 8-phase schedule, 256x256 tile, BK=64, 512 thr / 8 waves (2Mx4N).
// This round: MFMA16 reordered ks-outermost so dependent accumulate pairs
// (same acc register) are 8 MFMAs apart instead of adjacent.
// ---------------------------------------------------------------------------
#define BK2  64
#define NKT2 (KCAT / BK2)   /* 34 K-tiles */
#define NIT  (NKT2 / 2)     /* 17 iterations */

#define VMC4() asm volatile("s_waitcnt vmcnt(4)" ::: "memory")
#define VMC0() asm volatile("s_waitcnt vmcnt(0)" ::: "memory")
#define LGK8() asm volatile("s_waitcnt lgkmcnt(8)" ::: "memory")
#define LGK0() asm volatile("s_waitcnt lgkmcnt(0)" ::: "memory")
#define BARR() __builtin_amdgcn_s_barrier()
#define SBR()  __builtin_amdgcn_sched_barrier(0)
#define PRIO1() __builtin_amdgcn_s_setprio(1)
#define PRIO0() __builtin_amdgcn_s_setprio(0)

#define RD_A(D, QM)                                                            \
    _Pragma("unroll") for (int mi = 0; mi < 4; ++mi)                           \
    _Pragma("unroll") for (int ks = 0; ks < 2; ++ks) {                         \
        const int rl = ((QM) * 4 + mi) * 16 + lm;                              \
        const int ob = (rl * 128 + ks * 64 + quad * 16) ^ ((lm & 7) << 4);     \
        aF[mi * 2 + ks] = *(const bf16x8*)((const char*)&lds[D][wm][0] + ob);  \
    }

#define RD_B(D, QN, BF)                                                        \
    _Pragma("unroll") for (int ni = 0; ni < 2; ++ni)                           \
    _Pragma("unroll") for (int ks = 0; ks < 2; ++ks) {                         \
        const int rl = (wn & 1) * 64 + ((QN) * 2 + ni) * 16 + lm;              \
        const int ob = (rl * 128 + ks * 64 + quad * 16) ^ ((lm & 7) << 4);     \
        BF[ni * 2 + ks] =                                                      \
            *(const bf16x8*)((const char*)&lds[D][2 + (wn >> 1)][0] + ob);     \
    }

#define MFMA16(QM, QN, BF)                                                     \
    _Pragma("unroll") for (int ks = 0; ks < 2; ++ks)                           \
    _Pragma("unroll") for (int mi = 0; mi < 4; ++mi)                           \
    _Pragma("unroll") for (int ni = 0; ni < 2; ++ni)                           \
        acc[(QM) * 4 + mi][(QN) * 2 + ni] =                                    \
            __builtin_amdgcn_mfma_f32_16x16x32_bf16(                           \
                aF[mi * 2 + ks], BF[ni * 2 + ks],                              \
                acc[(QM) * 4 + mi][(QN) * 2 + ni], 0, 0, 0);

__global__ __launch_bounds__(512, 2) void gemm_main(const unsigned short* __restrict__ xcat,
                                                    const unsigned short* __restrict__ wcat,
                                                    const float* __restrict__ bias,
                                                    float* __restrict__ out) {
    __shared__ short lds[2][4][8192];   // 128 KiB
    const int tid = threadIdx.x;
    const int lane = tid & 63, wv = tid >> 6;
    const int wm = wv >> 2, wn = wv & 3;
    const int quad = lane >> 4, lm = lane & 15;

    const int orig = blockIdx.x;
    const int swz = (orig & 7) * ((int)gridDim.x >> 3) + (orig >> 3);
    const int col0 = (swz & 7) * 256;
    const int row0 = (swz >> 3) * 256;

    const int rbase = wv * 8 + (lane >> 3);
    const int csrc = ((((lane & 7) * 16) ^ (((lane >> 3) & 7) << 4)) >> 1);

    auto stage = [&](int buf, int part, int gk) {
        const int half = part & 1;
        const unsigned short* g = (part < 2)
            ? xcat + (size_t)(row0 + half * 128) * KCAT
            : wcat + (size_t)(col0 + half * 128) * KCAT;
        short* dbase = &lds[buf][part][0] + wv * 512;
#pragma unroll
        for (int j = 0; j < 2; ++j)
            async16(g + (size_t)(j * 64 + rbase) * KCAT + gk * 64 + csrc,
                    (void*)(dbase + j * 4096));
    };

    f32x4 acc[8][4];
    f32x4 zero = {0.f, 0.f, 0.f, 0.f};
#pragma unroll
    for (int i = 0; i < 8; ++i)
#pragma unroll
        for (int j = 0; j < 4; ++j) acc[i][j] = zero;

    bf16x8 aF[8];
    bf16x8 bF0[4], bF1[4];

    // prologue: buf0 <- kt0 (A+B), buf1 <- kt1 (B only)
    stage(0, 0, 0); stage(0, 1, 0); stage(0, 2, 0); stage(0, 3, 0);
    stage(1, 2, 1); stage(1, 3, 1);
    VMC4();
    BARR();
    RD_B(0, 0, bF0)

    for (int it = 0; it < NIT - 1; ++it) {
        // ---- K-tile 2it (buf 0) ----
        // P0
        RD_A(0, 0)
        stage(1, 0, 2 * it + 1); LGK8();
        BARR(); LGK0(); SBR(); PRIO1(); MFMA16(0, 0, bF0) PRIO0(); BARR();
        // P1
        RD_B(0, 1, bF1)
        stage(1, 1, 2 * it + 1);
        BARR(); LGK0(); SBR(); PRIO1(); MFMA16(0, 1, bF1) PRIO0(); BARR();
        // P2
        RD_A(0, 1)
        stage(0, 2, 2 * it + 2);
        BARR(); LGK0(); SBR(); PRIO1(); MFMA16(1, 1, bF1) PRIO0(); BARR();
        // P3  (+ read NEXT tile's bF0 from buf1, landed at VMC4)
        stage(0, 3, 2 * it + 2);
        BARR(); PRIO1(); MFMA16(1, 0, bF0) PRIO0(); VMC4();
        RD_B(1, 0, bF0)
        BARR();

        // ---- K-tile 2it+1 (buf 1) ----
        // P4
        RD_A(1, 0)
        stage(0, 0, 2 * it + 2); LGK8();
        BARR(); LGK0(); SBR(); PRIO1(); MFMA16(0, 0, bF0) PRIO0(); BARR();
        // P5
        RD_B(1, 1, bF1)
        stage(0, 1, 2 * it + 2);
        BARR(); LGK0(); SBR(); PRIO1(); MFMA16(0, 1, bF1) PRIO0(); BARR();
        // P6
        RD_A(1, 1)
        stage(1, 2, 2 * it + 3);
        BARR(); LGK0(); SBR(); PRIO1(); MFMA16(1, 1, bF1) PRIO0(); BARR();
        // P7  (+ read next buf0-tile's bF0, landed at VMC4)
        stage(1, 3, 2 * it + 3);
        BARR(); PRIO1(); MFMA16(1, 0, bF0) PRIO0(); VMC4();
        RD_B(0, 0, bF0)
        BARR();
    }

    // ---- peeled last iteration (kt 32/33) ----
    // P0
    RD_A(0, 0)
    stage(1, 0, 2 * (NIT - 1) + 1); LGK8();
    BARR(); LGK0(); SBR(); PRIO1(); MFMA16(0, 0, bF0) PRIO0(); BARR();
    // P1
    RD_B(0, 1, bF1)
    stage(1, 1, 2 * (NIT - 1) + 1);
    BARR(); LGK0(); SBR(); PRIO1(); MFMA16(0, 1, bF1) PRIO0(); BARR();
    // P2
    RD_A(0, 1)
    BARR(); LGK0(); SBR(); PRIO1(); MFMA16(1, 1, bF1) PRIO0(); BARR();
    // P3 — drain everything, then read kt33's bF0
    BARR(); PRIO1(); MFMA16(1, 0, bF0) PRIO0(); VMC0();
    RD_B(1, 0, bF0)
    BARR();
    // P4
    RD_A(1, 0)
    BARR(); LGK0(); SBR(); PRIO1(); MFMA16(0, 0, bF0) PRIO0(); BARR();
    // P5
    RD_B(1, 1, bF1)
    BARR(); LGK0(); SBR(); PRIO1(); MFMA16(0, 1, bF1) PRIO0(); BARR();
    // P6
    RD_A(1, 1)
    BARR(); LGK0(); SBR(); PRIO1(); MFMA16(1, 1, bF1) PRIO0(); BARR();
    // P7
    PRIO1(); MFMA16(1, 0, bF0) PRIO0();

    // epilogue
#pragma unroll
    for (int ni = 0; ni < 4; ++ni) {
        int col = col0 + wn * 64 + ni * 16 + lm;
        float bv = bias[col];
#pragma unroll
        for (int mi = 0; mi < 8; ++mi) {
            int rbase2 = row0 + wm * 128 + mi * 16 + quad * 4;
#pragma unroll
            for (int e = 0; e < 4; ++e)
                out[(size_t)(rbase2 + e) * DOUT + col] = acc[mi][ni][e] + bv;
        }
    }
}

extern "C" void kernel_launch(void* const* d_in, const int* in_sizes, int n_in,
                              void* d_out, int out_size, void* d_ws, size_t ws_size,
                              hipStream_t stream) {
    const float* x     = (const float*)d_in[0];
    const float* W     = (const float*)d_in[1];
    const float* bias  = (const float*)d_in[2];
    const float* A_all = (const float*)d_in[3];
    const float* B_all = (const float*)d_in[4];
    const int*   lidx  = (const int*)d_in[5];
    float* out = (float*)d_out;

    char* ws = (char*)d_ws;
    unsigned short* xcat = (unsigned short*)ws;
    unsigned short* wcat = (unsigned short*)(ws + (size_t)N_TOK * KCAT * 2);
    unsigned short* acat = (unsigned short*)(ws + (size_t)N_TOK * KCAT * 2
                                                + (size_t)DOUT * KCAT * 2);

    prep_w<<<2240, 256, 0, stream>>>(W, A_all, B_all, wcat, acat);
    xu_gemm<<<N_TOK / 128, 512, 0, stream>>>(x, acat, lidx, xcat);
    gemm_main<<<dim3((N_TOK / 256) * (DOUT / 256)), 512, 0, stream>>>(xcat, wcat, bias, out);
}